// Round 1
// 385.058 us; speedup vs baseline: 1.4541x; 1.4541x over previous
//
#include <hip/hip_runtime.h>

// GAT layer: B=8, N=1024, F_IN=25, H=8, D=16, f32 I/O.
// out0 = relu(h_prime) (8,1024,128) f32 ; out1 = alpha (8,8,1024,1024) f32
#define NEG_INF_F (-9.0e15f)
#define L2E 1.44269504f

typedef short short8_t __attribute__((ext_vector_type(8)));
typedef float fltx4    __attribute__((ext_vector_type(4)));
typedef int   intx4    __attribute__((ext_vector_type(4)));
typedef unsigned int uint32;

__device__ __forceinline__ unsigned short f2bf(float f) {
    uint32 u = __float_as_uint(f);
    u += 0x7FFFu + ((u >> 16) & 1u);   // RNE
    return (unsigned short)(u >> 16);
}

// ---------------------------------------------------------------------------
// prep_once: per (bh, n): Wh row (f32 -> bf16, MFMA B-frag layout in ws),
// ei = Wh.a_src, ej = Wh.a_dst (f32 in ws). Runs ONCE per (b,h) row.
//   whb[ bh*16384 + ((n>>5)*64 + ((n>>3)&3)*16 + d)*8 + (n&7) ] = Wh[n][d]
// ---------------------------------------------------------------------------
__global__ __launch_bounds__(256) void prep_once(
    const float* __restrict__ x,      // (8,1024,25)
    const float* __restrict__ W,      // (8,25,16)
    const float* __restrict__ a,      // (8,32)
    float* __restrict__ ei_ws,        // (64,1024)
    float* __restrict__ ej_ws,        // (64,1024)
    unsigned short* __restrict__ whb) // (64,32,64,8) bf16
{
    int t  = blockIdx.x * 256 + threadIdx.x;   // 65536
    int bh = t >> 10, n = t & 1023;
    int b  = bh >> 3, h = bh & 7;

    const float* xr = x + ((size_t)(b * 1024 + n)) * 25;
    const float* Wp = W + h * 400;
    const float* ap = a + h * 32;

    float xf[25];
    #pragma unroll
    for (int f = 0; f < 25; ++f) xf[f] = xr[f];

    int base = ((bh * 32 + (n >> 5)) * 64 + ((n >> 3) & 3) * 16) * 8 + (n & 7);
    float vi = 0.f, vj = 0.f;
    #pragma unroll
    for (int d = 0; d < 16; ++d) {
        float s = 0.f;
        #pragma unroll
        for (int f = 0; f < 25; ++f) s += xf[f] * Wp[f * 16 + d];
        vi += s * ap[d];
        vj += s * ap[16 + d];
        whb[base + d * 8] = f2bf(s);
    }
    ei_ws[t] = vi;
    ej_ws[t] = vj;
}

// ---------------------------------------------------------------------------
// gat_main: one block per (b, chunk, h).
// XCD-aware decode: h = blk>>7 so the 8 head-blocks sharing one adj chunk
// have identical blk%8 -> same XCD -> shared L2 for adj (round-robin
// dispatch maps blk%8 -> XCD on MI355X). All 1024 blocks co-resident (4/CU).
// 4 waves x 16 rows. Zero LDS. ej held in 16 registers per lane.
// ---------------------------------------------------------------------------
__global__ __launch_bounds__(256) void gat_main(
    const int*   __restrict__ adj,    // (8,1024,1024)
    const float* __restrict__ ei_ws,
    const float* __restrict__ ej_ws,
    const unsigned short* __restrict__ whb,
    float* __restrict__ out0,         // (8,1024,128)
    float* __restrict__ out1)         // (8,8,1024,1024)
{
    const int blk   = blockIdx.x;
    const int h     = blk >> 7;        // slowest -> blk%8 invariant across h
    const int bc    = blk & 127;
    const int b     = bc >> 4;
    const int chunk = bc & 15;
    const int bh    = b * 8 + h;
    const int wave  = threadIdx.x >> 6;
    const int lane  = threadIdx.x & 63;
    const int mrow  = lane & 15;
    const int quad  = lane >> 4;
    const int i0    = chunk * 64 + wave * 16;

    // ej for this lane's 16 columns -> registers, reused for all 16 rows
    const fltx4* ej4 = (const fltx4*)(ej_ws + bh * 1024);
    fltx4 ejr[4];
    #pragma unroll
    for (int j0 = 0; j0 < 4; ++j0) ejr[j0] = ej4[j0 * 64 + lane];

    const float* eib = ei_ws + bh * 1024;
    float* abase = out1 + (size_t)bh * 1024 * 1024;

    // ---- Phase A: softmax rows i0..i0+15 ----
    for (int r = 0; r < 16; ++r) {
        int i = i0 + r;
        float s_ei = eib[i];
        const intx4* adj4 = (const intx4*)(adj + ((size_t)b * 1024 + i) * 1024);

        float p[16];
        float sum = 0.f;
        #pragma unroll
        for (int j0 = 0; j0 < 4; ++j0) {
            intx4 av = adj4[j0 * 64 + lane];
            fltx4 ev = ejr[j0];
            float p0 = av.x ? exp2f((s_ei + ev.x) * L2E) : 0.f;
            float p1 = av.y ? exp2f((s_ei + ev.y) * L2E) : 0.f;
            float p2 = av.z ? exp2f((s_ei + ev.z) * L2E) : 0.f;
            float p3 = av.w ? exp2f((s_ei + ev.w) * L2E) : 0.f;
            p[j0 * 4 + 0] = p0; p[j0 * 4 + 1] = p1;
            p[j0 * 4 + 2] = p2; p[j0 * 4 + 3] = p3;
            sum += (p0 + p1) + (p2 + p3);
        }
        #pragma unroll
        for (int off = 32; off; off >>= 1) sum += __shfl_xor(sum, off);

        float rinv;
        if (sum > 0.f) {
            rinv = __builtin_amdgcn_rcpf(sum);   // 1-ulp rcp; alpha tol is bf16-dominated
        } else {
            rinv = 1.0f;   // fully-masked row -> uniform 1/1024
            #pragma unroll
            for (int k = 0; k < 16; ++k) p[k] = 1.0f / 1024.0f;
        }

        float* arow = abase + (size_t)i * 1024;
        #pragma unroll
        for (int j0 = 0; j0 < 4; ++j0) {
            fltx4 st;
            st.x = p[j0 * 4 + 0] * rinv;
            st.y = p[j0 * 4 + 1] * rinv;
            st.z = p[j0 * 4 + 2] * rinv;
            st.w = p[j0 * 4 + 3] * rinv;
            *(fltx4*)(arow + (j0 * 64 + lane) * 4) = st;
        }
    }

    // Same-wave RAW through memory only: each wave re-reads exactly the rows
    // it wrote. Needs vmcnt(0) ordering, NOT an agent-scope fence (which on
    // multi-XCD gfx950 emits buffer_wbl2/buffer_inv and nukes the whole L2).
    __builtin_amdgcn_fence(__ATOMIC_ACQ_REL, "workgroup");

    // ---- Phase B: h_prime(16x16) = alpha(16x1024) @ Wh(1024x16) ----
    const float* aptr = abase + (size_t)(i0 + mrow) * 1024 + quad * 8;
    const unsigned short* bbase = whb + (size_t)bh * 16384;
    fltx4 acc = {0.f, 0.f, 0.f, 0.f};
    #pragma unroll 4
    for (int ks = 0; ks < 32; ++ks) {
        fltx4 a0 = *(const fltx4*)(aptr + ks * 32);
        fltx4 a1 = *(const fltx4*)(aptr + ks * 32 + 4);
        short8_t afr;
        #pragma unroll
        for (int q = 0; q < 4; ++q) {
            afr[q]     = (short)f2bf(a0[q]);
            afr[4 + q] = (short)f2bf(a1[q]);
        }
        short8_t bfr = *(const short8_t*)(bbase + ((ks * 64 + lane) << 3));
        acc = __builtin_amdgcn_mfma_f32_16x16x32_bf16(afr, bfr, acc, 0, 0, 0);
    }

    // C layout: col = mrow (=d), row = quad*4 + reg
    #pragma unroll
    for (int r = 0; r < 4; ++r) {
        int i = i0 + quad * 4 + r;
        float v = acc[r] > 0.f ? acc[r] : 0.f;
        out0[((size_t)(b * 1024 + i)) * 128 + h * 16 + mrow] = v;
    }
}

// ---------------------------------------------------------------------------
// Fallback: round-3 fused kernel (known correct), used if ws_size too small.
// ---------------------------------------------------------------------------
__global__ __launch_bounds__(256) void gat_fused(
    const float* __restrict__ x, const int* __restrict__ adj,
    const float* __restrict__ W, const float* __restrict__ a,
    float* __restrict__ out0, float* __restrict__ out1)
{
    __shared__ __align__(16) unsigned short whb[32 * 64 * 8];
    __shared__ __align__(16) float ej_lds[1024];
    __shared__ float ei_lds[64];
    __shared__ float wa[64];

    const int bh    = blockIdx.x >> 4;
    const int chunk = blockIdx.x & 15;
    const int b     = bh >> 3;
    const int h     = bh & 7;
    const int tid   = threadIdx.x;
    const int wave  = tid >> 6;
    const int lane  = tid & 63;
    const int mrow  = lane & 15;
    const int quad  = lane >> 4;

    const float* Wp = W + h * 400;
    const float* ap = a + h * 32;
    const float* xb = x + (size_t)b * 1024 * 25;

    if (tid < 50) {
        int f = tid % 25, which = tid / 25;
        float s = 0.f;
        #pragma unroll
        for (int d = 0; d < 16; ++d) s += Wp[f * 16 + d] * ap[which * 16 + d];
        wa[which * 32 + f] = s;
    }
    __syncthreads();

    for (int s = 0; s < 4; ++s) {
        int n = tid + (s << 8);
        const float* xr = xb + n * 25;
        float xf[25];
        #pragma unroll
        for (int f = 0; f < 25; ++f) xf[f] = xr[f];
        float vi = 0.f, vj = 0.f;
        #pragma unroll
        for (int f = 0; f < 25; ++f) { vi += xf[f] * wa[f]; vj += xf[f] * wa[32 + f]; }
        ej_lds[n] = vj;
        if ((n >> 6) == chunk) ei_lds[n & 63] = vi;
        int base = (((n >> 5) * 64 + ((n >> 3) & 3) * 16) << 3) + (n & 7);
        #pragma unroll
        for (int d = 0; d < 16; ++d) {
            float s2 = 0.f;
            #pragma unroll
            for (int f = 0; f < 25; ++f) s2 += xf[f] * Wp[f * 16 + d];
            whb[base + d * 8] = f2bf(s2);
        }
    }
    __syncthreads();

    const int i0 = chunk * 64 + wave * 16;
    float* abase = out1 + (size_t)bh * 1024 * 1024;
    const fltx4* ej4 = (const fltx4*)ej_lds;

    for (int r = 0; r < 16; ++r) {
        int i = i0 + r;
        float s_ei = ei_lds[wave * 16 + r];
        const intx4* adj4 = (const intx4*)(adj + ((size_t)b * 1024 + i) * 1024);
        float p[16];
        float sum = 0.f;
        #pragma unroll
        for (int j0 = 0; j0 < 4; ++j0) {
            intx4 av = adj4[j0 * 64 + lane];
            fltx4 ev = ej4[j0 * 64 + lane];
            float p0 = av.x ? exp2f((s_ei + ev.x) * L2E) : 0.f;
            float p1 = av.y ? exp2f((s_ei + ev.y) * L2E) : 0.f;
            float p2 = av.z ? exp2f((s_ei + ev.z) * L2E) : 0.f;
            float p3 = av.w ? exp2f((s_ei + ev.w) * L2E) : 0.f;
            p[j0 * 4 + 0] = p0; p[j0 * 4 + 1] = p1;
            p[j0 * 4 + 2] = p2; p[j0 * 4 + 3] = p3;
            sum += (p0 + p1) + (p2 + p3);
        }
        #pragma unroll
        for (int off = 32; off; off >>= 1) sum += __shfl_xor(sum, off);
        float rinv;
        if (sum > 0.f) {
            rinv = __builtin_amdgcn_rcpf(sum);
        } else {
            rinv = 1.0f;
            #pragma unroll
            for (int k = 0; k < 16; ++k) p[k] = 1.0f / 1024.0f;
        }
        float* arow = abase + (size_t)i * 1024;
        #pragma unroll
        for (int j0 = 0; j0 < 4; ++j0) {
            fltx4 st;
            st.x = p[j0 * 4 + 0] * rinv; st.y = p[j0 * 4 + 1] * rinv;
            st.z = p[j0 * 4 + 2] * rinv; st.w = p[j0 * 4 + 3] * rinv;
            *(fltx4*)(arow + (j0 * 64 + lane) * 4) = st;
        }
    }

    __builtin_amdgcn_fence(__ATOMIC_ACQ_REL, "workgroup");

    const float* aptr = abase + (size_t)(i0 + mrow) * 1024 + quad * 8;
    fltx4 acc = {0.f, 0.f, 0.f, 0.f};
    for (int ks = 0; ks < 32; ++ks) {
        fltx4 a0 = *(const fltx4*)(aptr + ks * 32);
        fltx4 a1 = *(const fltx4*)(aptr + ks * 32 + 4);
        short8_t afr;
        #pragma unroll
        for (int q = 0; q < 4; ++q) {
            afr[q]     = (short)f2bf(a0[q]);
            afr[4 + q] = (short)f2bf(a1[q]);
        }
        short8_t bfr = *(const short8_t*)&whb[((ks * 64 + lane) << 3)];
        acc = __builtin_amdgcn_mfma_f32_16x16x32_bf16(afr, bfr, acc, 0, 0, 0);
    }
    #pragma unroll
    for (int r = 0; r < 4; ++r) {
        int i = i0 + quad * 4 + r;
        float v = acc[r] > 0.f ? acc[r] : 0.f;
        out0[((size_t)(b * 1024 + i)) * 128 + h * 16 + mrow] = v;
    }
}

extern "C" void kernel_launch(void* const* d_in, const int* in_sizes, int n_in,
                              void* d_out, int out_size, void* d_ws, size_t ws_size,
                              hipStream_t stream) {
    const float* x   = (const float*)d_in[0];
    const int*   adj = (const int*)d_in[1];
    const float* W   = (const float*)d_in[2];
    const float* a   = (const float*)d_in[3];

    float* out0 = (float*)d_out;                    // (8,1024,128)
    float* out1 = out0 + (size_t)8 * 1024 * 128;    // (8,8,1024,1024)

    const size_t WHB_BYTES = (size_t)64 * 16384 * 2;      // 2 MB
    const size_t EI_BYTES  = (size_t)64 * 1024 * 4;       // 256 KB
    const size_t NEED      = WHB_BYTES + 2 * EI_BYTES;    // 2.5 MB

    if (ws_size >= NEED) {
        unsigned short* whb = (unsigned short*)d_ws;
        float* ei_ws = (float*)((char*)d_ws + WHB_BYTES);
        float* ej_ws = ei_ws + 64 * 1024;
        prep_once<<<256, 256, 0, stream>>>(x, W, a, ei_ws, ej_ws, whb);
        gat_main<<<1024, 256, 0, stream>>>(adj, ei_ws, ej_ws, whb, out0, out1);
    } else {
        gat_fused<<<1024, 256, 0, stream>>>(x, adj, W, a, out0, out1);
    }
}

// Round 2
// 330.636 us; speedup vs baseline: 1.6935x; 1.1646x over previous
//
#include <hip/hip_runtime.h>

// GAT layer: B=8, N=1024, F_IN=25, H=8, D=16, f32 I/O.
// out0 = relu(h_prime) (8,1024,128) f32 ; out1 = alpha (8,8,1024,1024) f32
//
// Key identity: e[i,j] = ei[i] + ej[j]; softmax over j is invariant to the
// per-row constant ei[i]  =>  alpha[i,j] = mask*exp(ej[j]) / sum_j mask*exp(ej[j]).
// So the inner loop needs NO transcendentals: exp(ej) is 16 regs per lane,
// computed once per block.
#define L2E 1.44269504f

typedef short short8_t  __attribute__((ext_vector_type(8)));
typedef float fltx4     __attribute__((ext_vector_type(4)));
typedef int   intx4     __attribute__((ext_vector_type(4)));
typedef unsigned short ushort4_t __attribute__((ext_vector_type(4)));
typedef unsigned int uint32;

__device__ __forceinline__ unsigned short f2bf(float f) {
    uint32 u = __float_as_uint(f);
    u += 0x7FFFu + ((u >> 16) & 1u);   // RNE
    return (unsigned short)(u >> 16);
}

// ---------------------------------------------------------------------------
// prep_once: per (bh, n): Wh row (f32 -> bf16, MFMA B-frag layout in ws),
// ej = Wh.a_dst (f32 in ws). (ei is NOT needed: it cancels in softmax.)
//   whb[ bh*16384 + ((n>>5)*64 + ((n>>3)&3)*16 + d)*8 + (n&7) ] = Wh[n][d]
// ---------------------------------------------------------------------------
__global__ __launch_bounds__(256) void prep_once(
    const float* __restrict__ x,      // (8,1024,25)
    const float* __restrict__ W,      // (8,25,16)
    const float* __restrict__ a,      // (8,32)
    float* __restrict__ ej_ws,        // (64,1024)
    unsigned short* __restrict__ whb) // (64,32,64,8) bf16
{
    int t  = blockIdx.x * 256 + threadIdx.x;   // 65536
    int bh = t >> 10, n = t & 1023;
    int b  = bh >> 3, h = bh & 7;

    const float* xr = x + ((size_t)(b * 1024 + n)) * 25;
    const float* Wp = W + h * 400;
    const float* ap = a + h * 32;

    float xf[25];
    #pragma unroll
    for (int f = 0; f < 25; ++f) xf[f] = xr[f];

    int base = ((bh * 32 + (n >> 5)) * 64 + ((n >> 3) & 3) * 16) * 8 + (n & 7);
    float vj = 0.f;
    #pragma unroll
    for (int d = 0; d < 16; ++d) {
        float s = 0.f;
        #pragma unroll
        for (int f = 0; f < 25; ++f) s += xf[f] * Wp[f * 16 + d];
        vj += s * ap[16 + d];
        whb[base + d * 8] = f2bf(s);
    }
    ej_ws[t] = vj;
}

// ---------------------------------------------------------------------------
// gat_main: one block per (b, 32-row chunk, h). 2048 blocks x 256 thr.
// XCD-aware decode: blk%8 = XCD, next 3 bits = h -> the 8 head-blocks that
// share one adj chunk are CONSECUTIVE in the same XCD's dispatch sequence
// -> adj read once per XCD group, 8x reuse from that XCD's L2.
// Phase A: softmax rows (no exp in loop), f32 alpha -> global (nontemporal,
// never re-read), bf16 alpha -> LDS (XOR-swizzled, MFMA A-frag source).
// Phase B: h_prime = alpha @ Wh entirely from LDS. 64 KB LDS -> 2 blocks/CU.
// ---------------------------------------------------------------------------
__global__ __launch_bounds__(256) void gat_main(
    const int*   __restrict__ adj,    // (8,1024,1024)
    const float* __restrict__ ej_ws,
    const unsigned short* __restrict__ whb,
    float* __restrict__ out0,         // (8,1024,128)
    float* __restrict__ out1)         // (8,8,1024,1024)
{
    __shared__ __align__(16) unsigned short palds[32 * 1024];  // 64 KB bf16 alpha

    const int blk   = blockIdx.x;
    const int x8    = blk & 7;          // XCD id (round-robin dispatch)
    const int h     = (blk >> 3) & 7;   // h fastest within an XCD -> adj reuse
    const int s     = blk >> 6;         // 0..31
    const int c     = s * 8 + x8;       // 0..255 = (b, chunk)
    const int b     = c >> 5;
    const int chunk = c & 31;           // 32-row chunk
    const int bh    = b * 8 + h;
    const int wave  = threadIdx.x >> 6;
    const int lane  = threadIdx.x & 63;
    const int i0    = chunk * 32;

    // exp(ej) for this lane's 16 columns -> registers, computed ONCE
    const fltx4* ej4 = (const fltx4*)(ej_ws + bh * 1024);
    fltx4 expr_[4];
    #pragma unroll
    for (int j0 = 0; j0 < 4; ++j0) {
        fltx4 e = ej4[j0 * 64 + lane];
        fltx4 r;
        r.x = exp2f(e.x * L2E); r.y = exp2f(e.y * L2E);
        r.z = exp2f(e.z * L2E); r.w = exp2f(e.w * L2E);
        expr_[j0] = r;
    }

    float* abase = out1 + (size_t)bh * 1024 * 1024;
    char*  ldsb  = (char*)palds;

    // ---- Phase A: 8 rows per wave ----
    for (int r = 0; r < 8; ++r) {
        const int rl = wave * 8 + r;        // block-local row 0..31
        const int i  = i0 + rl;
        const intx4* adj4 = (const intx4*)(adj + ((size_t)b * 1024 + i) * 1024);

        float p[16];
        float sum = 0.f;
        #pragma unroll
        for (int j0 = 0; j0 < 4; ++j0) {
            intx4 av = adj4[j0 * 64 + lane];
            fltx4 ev = expr_[j0];
            float p0 = av.x ? ev.x : 0.f;
            float p1 = av.y ? ev.y : 0.f;
            float p2 = av.z ? ev.z : 0.f;
            float p3 = av.w ? ev.w : 0.f;
            p[j0 * 4 + 0] = p0; p[j0 * 4 + 1] = p1;
            p[j0 * 4 + 2] = p2; p[j0 * 4 + 3] = p3;
            sum += (p0 + p1) + (p2 + p3);
        }
        #pragma unroll
        for (int off = 32; off; off >>= 1) sum += __shfl_xor(sum, off);

        float rinv;
        if (sum > 0.f) {
            rinv = __builtin_amdgcn_rcpf(sum);
        } else {
            rinv = 1.0f;   // fully-masked row -> uniform 1/1024
            #pragma unroll
            for (int k = 0; k < 16; ++k) p[k] = 1.0f / 1024.0f;
        }

        float* arow = abase + (size_t)i * 1024;
        const int swz  = (rl & 7) << 4;
        char* lrow = ldsb + rl * 2048;
        #pragma unroll
        for (int j0 = 0; j0 < 4; ++j0) {
            fltx4 st;
            st.x = p[j0 * 4 + 0] * rinv;
            st.y = p[j0 * 4 + 1] * rinv;
            st.z = p[j0 * 4 + 2] * rinv;
            st.w = p[j0 * 4 + 3] * rinv;
            // streaming output, never re-read -> nontemporal, keep L2 for adj
            __builtin_nontemporal_store(st, (fltx4*)(arow + (j0 * 64 + lane) * 4));
            ushort4_t bv;
            bv.x = f2bf(st.x); bv.y = f2bf(st.y);
            bv.z = f2bf(st.z); bv.w = f2bf(st.w);
            *(ushort4_t*)(lrow + (((j0 * 512) + lane * 8) ^ swz)) = bv;
        }
    }

    __syncthreads();   // LDS visibility; no global fence needed anymore

    // ---- Phase B: h_prime(16x16) = alpha(16x1024) @ Wh(1024x16), alpha from LDS ----
    if (wave < 2) {
        const int mrow = lane & 15;
        const int quad = lane >> 4;
        const int rl   = wave * 16 + mrow;           // A-row (block-local)
        const int swz  = (rl & 7) << 4;
        char* lrow = ldsb + rl * 2048;
        const unsigned short* bbase = whb + (size_t)bh * 16384;

        fltx4 acc = {0.f, 0.f, 0.f, 0.f};
        #pragma unroll 4
        for (int ks = 0; ks < 32; ++ks) {
            short8_t afr = *(const short8_t*)(lrow + ((ks * 64 + quad * 16) ^ swz));
            short8_t bfr = *(const short8_t*)(bbase + ((ks * 64 + lane) << 3));
            acc = __builtin_amdgcn_mfma_f32_16x16x32_bf16(afr, bfr, acc, 0, 0, 0);
        }

        // C layout: col = mrow (=d), row = quad*4 + reg
        #pragma unroll
        for (int r = 0; r < 4; ++r) {
            int i = i0 + wave * 16 + quad * 4 + r;
            float v = acc[r] > 0.f ? acc[r] : 0.f;
            out0[((size_t)(b * 1024 + i)) * 128 + h * 16 + mrow] = v;
        }
    }
}

// ---------------------------------------------------------------------------
// Fallback: fused kernel (known correct), used if ws_size too small.
// ---------------------------------------------------------------------------
__global__ __launch_bounds__(256) void gat_fused(
    const float* __restrict__ x, const int* __restrict__ adj,
    const float* __restrict__ W, const float* __restrict__ a,
    float* __restrict__ out0, float* __restrict__ out1)
{
    __shared__ __align__(16) unsigned short whb[32 * 64 * 8];
    __shared__ __align__(16) float ej_lds[1024];
    __shared__ float ei_lds[64];
    __shared__ float wa[64];

    const int bh    = blockIdx.x >> 4;
    const int chunk = blockIdx.x & 15;
    const int b     = bh >> 3;
    const int h     = bh & 7;
    const int tid   = threadIdx.x;
    const int wave  = tid >> 6;
    const int lane  = tid & 63;
    const int mrow  = lane & 15;
    const int quad  = lane >> 4;

    const float* Wp = W + h * 400;
    const float* ap = a + h * 32;
    const float* xb = x + (size_t)b * 1024 * 25;

    if (tid < 50) {
        int f = tid % 25, which = tid / 25;
        float s = 0.f;
        #pragma unroll
        for (int d = 0; d < 16; ++d) s += Wp[f * 16 + d] * ap[which * 16 + d];
        wa[which * 32 + f] = s;
    }
    __syncthreads();

    for (int s = 0; s < 4; ++s) {
        int n = tid + (s << 8);
        const float* xr = xb + n * 25;
        float xf[25];
        #pragma unroll
        for (int f = 0; f < 25; ++f) xf[f] = xr[f];
        float vi = 0.f, vj = 0.f;
        #pragma unroll
        for (int f = 0; f < 25; ++f) { vi += xf[f] * wa[f]; vj += xf[f] * wa[32 + f]; }
        ej_lds[n] = vj;
        if ((n >> 6) == chunk) ei_lds[n & 63] = vi;
        int base = (((n >> 5) * 64 + ((n >> 3) & 3) * 16) << 3) + (n & 7);
        #pragma unroll
        for (int d = 0; d < 16; ++d) {
            float s2 = 0.f;
            #pragma unroll
            for (int f = 0; f < 25; ++f) s2 += xf[f] * Wp[f * 16 + d];
            whb[base + d * 8] = f2bf(s2);
        }
    }
    __syncthreads();

    const int i0 = chunk * 64 + wave * 16;
    float* abase = out1 + (size_t)bh * 1024 * 1024;
    const fltx4* ej4 = (const fltx4*)ej_lds;

    for (int r = 0; r < 16; ++r) {
        int i = i0 + r;
        float s_ei = ei_lds[wave * 16 + r];
        const intx4* adj4 = (const intx4*)(adj + ((size_t)b * 1024 + i) * 1024);
        float p[16];
        float sum = 0.f;
        #pragma unroll
        for (int j0 = 0; j0 < 4; ++j0) {
            intx4 av = adj4[j0 * 64 + lane];
            fltx4 ev = ej4[j0 * 64 + lane];
            float p0 = av.x ? exp2f((s_ei + ev.x) * L2E) : 0.f;
            float p1 = av.y ? exp2f((s_ei + ev.y) * L2E) : 0.f;
            float p2 = av.z ? exp2f((s_ei + ev.z) * L2E) : 0.f;
            float p3 = av.w ? exp2f((s_ei + ev.w) * L2E) : 0.f;
            p[j0 * 4 + 0] = p0; p[j0 * 4 + 1] = p1;
            p[j0 * 4 + 2] = p2; p[j0 * 4 + 3] = p3;
            sum += (p0 + p1) + (p2 + p3);
        }
        #pragma unroll
        for (int off = 32; off; off >>= 1) sum += __shfl_xor(sum, off);
        float rinv;
        if (sum > 0.f) {
            rinv = __builtin_amdgcn_rcpf(sum);
        } else {
            rinv = 1.0f;
            #pragma unroll
            for (int k = 0; k < 16; ++k) p[k] = 1.0f / 1024.0f;
        }
        float* arow = abase + (size_t)i * 1024;
        #pragma unroll
        for (int j0 = 0; j0 < 4; ++j0) {
            fltx4 st;
            st.x = p[j0 * 4 + 0] * rinv; st.y = p[j0 * 4 + 1] * rinv;
            st.z = p[j0 * 4 + 2] * rinv; st.w = p[j0 * 4 + 3] * rinv;
            *(fltx4*)(arow + (j0 * 64 + lane) * 4) = st;
        }
    }

    __builtin_amdgcn_fence(__ATOMIC_ACQ_REL, "workgroup");

    const float* aptr = abase + (size_t)(i0 + mrow) * 1024 + quad * 8;
    fltx4 acc = {0.f, 0.f, 0.f, 0.f};
    for (int ks = 0; ks < 32; ++ks) {
        fltx4 a0 = *(const fltx4*)(aptr + ks * 32);
        fltx4 a1 = *(const fltx4*)(aptr + ks * 32 + 4);
        short8_t afr;
        #pragma unroll
        for (int q = 0; q < 4; ++q) {
            afr[q]     = (short)f2bf(a0[q]);
            afr[4 + q] = (short)f2bf(a1[q]);
        }
        short8_t bfr = *(const short8_t*)&whb[((ks * 64 + lane) << 3)];
        acc = __builtin_amdgcn_mfma_f32_16x16x32_bf16(afr, bfr, acc, 0, 0, 0);
    }
    #pragma unroll
    for (int r = 0; r < 4; ++r) {
        int i = i0 + quad * 4 + r;
        float v = acc[r] > 0.f ? acc[r] : 0.f;
        out0[((size_t)(b * 1024 + i)) * 128 + h * 16 + mrow] = v;
    }
}

extern "C" void kernel_launch(void* const* d_in, const int* in_sizes, int n_in,
                              void* d_out, int out_size, void* d_ws, size_t ws_size,
                              hipStream_t stream) {
    const float* x   = (const float*)d_in[0];
    const int*   adj = (const int*)d_in[1];
    const float* W   = (const float*)d_in[2];
    const float* a   = (const float*)d_in[3];

    float* out0 = (float*)d_out;                    // (8,1024,128)
    float* out1 = out0 + (size_t)8 * 1024 * 128;    // (8,8,1024,1024)

    const size_t WHB_BYTES = (size_t)64 * 16384 * 2;      // 2 MB
    const size_t EJ_BYTES  = (size_t)64 * 1024 * 4;       // 256 KB
    const size_t NEED      = WHB_BYTES + EJ_BYTES;        // 2.25 MB

    if (ws_size >= NEED) {
        unsigned short* whb = (unsigned short*)d_ws;
        float* ej_ws = (float*)((char*)d_ws + WHB_BYTES);
        prep_once<<<256, 256, 0, stream>>>(x, W, a, ej_ws, whb);
        gat_main<<<2048, 256, 0, stream>>>(adj, ej_ws, whb, out0, out1);
    } else {
        gat_fused<<<1024, 256, 0, stream>>>(x, adj, W, a, out0, out1);
    }
}

// Round 3
// 314.988 us; speedup vs baseline: 1.7776x; 1.0497x over previous
//
#include <hip/hip_runtime.h>

// GAT layer: B=8, N=1024, F_IN=25, H=8, D=16, f32 I/O.
// out0 = relu(h_prime) (8,1024,128) f32 ; out1 = alpha (8,8,1024,1024) f32
//
// Key identity: e[i,j] = ei[i] + ej[j]; softmax over j is invariant to the
// per-row constant ei[i]  =>  alpha[i,j] = mask*exp(ej[j]) / sum_j mask*exp(ej[j]).
// So the inner loop needs NO transcendentals: exp(ej) is 16 regs per lane,
// computed once per block.
#define L2E 1.44269504f

typedef short short8_t  __attribute__((ext_vector_type(8)));
typedef float fltx4     __attribute__((ext_vector_type(4)));
typedef int   intx4     __attribute__((ext_vector_type(4)));
typedef unsigned short ushort4_t __attribute__((ext_vector_type(4)));
typedef unsigned int uint32;

__device__ __forceinline__ unsigned short f2bf(float f) {
    uint32 u = __float_as_uint(f);
    u += 0x7FFFu + ((u >> 16) & 1u);   // RNE
    return (unsigned short)(u >> 16);
}

// ---------------------------------------------------------------------------
// prep_once: per (bh, n): Wh row (f32 -> bf16, MFMA B-frag layout in ws),
// ej = Wh.a_dst (f32 in ws). (ei is NOT needed: it cancels in softmax.)
//   whb[ bh*16384 + ((n>>5)*64 + ((n>>3)&3)*16 + d)*8 + (n&7) ] = Wh[n][d]
// ---------------------------------------------------------------------------
__global__ __launch_bounds__(256) void prep_once(
    const float* __restrict__ x,      // (8,1024,25)
    const float* __restrict__ W,      // (8,25,16)
    const float* __restrict__ a,      // (8,32)
    float* __restrict__ ej_ws,        // (64,1024)
    unsigned short* __restrict__ whb) // (64,32,64,8) bf16
{
    int t  = blockIdx.x * 256 + threadIdx.x;   // 65536
    int bh = t >> 10, n = t & 1023;
    int b  = bh >> 3, h = bh & 7;

    const float* xr = x + ((size_t)(b * 1024 + n)) * 25;
    const float* Wp = W + h * 400;
    const float* ap = a + h * 32;

    float xf[25];
    #pragma unroll
    for (int f = 0; f < 25; ++f) xf[f] = xr[f];

    int base = ((bh * 32 + (n >> 5)) * 64 + ((n >> 3) & 3) * 16) * 8 + (n & 7);
    float vj = 0.f;
    #pragma unroll
    for (int d = 0; d < 16; ++d) {
        float s = 0.f;
        #pragma unroll
        for (int f = 0; f < 25; ++f) s += xf[f] * Wp[f * 16 + d];
        vj += s * ap[16 + d];
        whb[base + d * 8] = f2bf(s);
    }
    ej_ws[t] = vj;
}

// ---------------------------------------------------------------------------
// gat_main: one block per (b, 32-row chunk, h). 2048 blocks x 256 thr.
// XCD-aware decode: blk%8 = XCD, next 3 bits = h -> the 8 head-blocks that
// share one adj chunk are CONSECUTIVE in the same XCD's dispatch sequence
// -> adj read once per XCD group, 8x reuse from that XCD's L2.
// Phase A (latency-optimized): all 8 rows of a wave processed as a BATCH:
//   - all 32 adj loads issued up front (deep MLP),
//   - 8 lane-local sums, then 6 shuffle rounds as 8 interleaved chains
//     (reduction latency amortized 8x instead of serialized per row),
//   - batched normalize+store pass recomputing p from live adj regs.
// f32 alpha -> global nontemporal (never re-read; keep L2 for adj),
// bf16 alpha -> LDS (XOR-swizzled, MFMA A-frag source for Phase B).
// Phase B: h_prime = alpha(16x1024) @ Wh(1024x16) from LDS. 64 KB LDS.
// ---------------------------------------------------------------------------
__global__ __launch_bounds__(256) void gat_main(
    const int*   __restrict__ adj,    // (8,1024,1024)
    const float* __restrict__ ej_ws,
    const unsigned short* __restrict__ whb,
    float* __restrict__ out0,         // (8,1024,128)
    float* __restrict__ out1)         // (8,8,1024,1024)
{
    __shared__ __align__(16) unsigned short palds[32 * 1024];  // 64 KB bf16 alpha

    const int blk   = blockIdx.x;
    const int x8    = blk & 7;          // XCD id (round-robin dispatch)
    const int h     = (blk >> 3) & 7;   // h fastest within an XCD -> adj reuse
    const int s     = blk >> 6;         // 0..31
    const int c     = s * 8 + x8;       // 0..255 = (b, chunk)
    const int b     = c >> 5;
    const int chunk = c & 31;           // 32-row chunk
    const int bh    = b * 8 + h;
    const int wave  = threadIdx.x >> 6;
    const int lane  = threadIdx.x & 63;
    const int i0    = chunk * 32;

    // exp(ej) for this lane's 16 columns -> registers, computed ONCE
    const fltx4* ej4 = (const fltx4*)(ej_ws + bh * 1024);
    fltx4 expr_[4];
    #pragma unroll
    for (int j0 = 0; j0 < 4; ++j0) {
        fltx4 e = ej4[j0 * 64 + lane];
        fltx4 r;
        r.x = exp2f(e.x * L2E); r.y = exp2f(e.y * L2E);
        r.z = exp2f(e.z * L2E); r.w = exp2f(e.w * L2E);
        expr_[j0] = r;
    }

    float* abase = out1 + (size_t)bh * 1024 * 1024;
    char*  ldsb  = (char*)palds;

    // ---- Phase A: 8 rows per wave, fully batched ----
    // All 32 adj loads in flight before any use: ~190 VGPRs, still 2 waves/SIMD.
    const intx4* adjb = (const intx4*)(adj + ((size_t)b * 1024 + i0 + wave * 8) * 1024);
    intx4 av[8][4];
    #pragma unroll
    for (int r = 0; r < 8; ++r)
        #pragma unroll
        for (int j0 = 0; j0 < 4; ++j0)
            av[r][j0] = adjb[r * 256 + j0 * 64 + lane];

    // lane-local sums (independent across rows)
    float sum[8];
    #pragma unroll
    for (int r = 0; r < 8; ++r) {
        float s0 = 0.f;
        #pragma unroll
        for (int j0 = 0; j0 < 4; ++j0) {
            intx4 a4 = av[r][j0];
            fltx4 ev = expr_[j0];
            s0 += (a4.x ? ev.x : 0.f) + (a4.y ? ev.y : 0.f)
                + (a4.z ? ev.z : 0.f) + (a4.w ? ev.w : 0.f);
        }
        sum[r] = s0;
    }

    // 6 shuffle rounds, 8 interleaved independent chains
    #pragma unroll
    for (int off = 32; off; off >>= 1) {
        #pragma unroll
        for (int r = 0; r < 8; ++r) sum[r] += __shfl_xor(sum[r], off);
    }

    // batched normalize + store (p recomputed from live adj regs: 1 cndmask each)
    #pragma unroll
    for (int r = 0; r < 8; ++r) {
        const int rl = wave * 8 + r;        // block-local row 0..31
        const int i  = i0 + rl;
        const bool ok = sum[r] > 0.f;
        const float rinv = ok ? __builtin_amdgcn_rcpf(sum[r]) : 0.f;
        const float fb   = ok ? 0.f : (1.0f / 1024.0f);   // fully-masked row

        float* arow = abase + (size_t)i * 1024;
        const int swz  = (rl & 7) << 4;
        char* lrow = ldsb + rl * 2048;
        #pragma unroll
        for (int j0 = 0; j0 < 4; ++j0) {
            intx4 a4 = av[r][j0];
            fltx4 ev = expr_[j0];
            fltx4 st;
            st.x = a4.x ? ev.x * rinv + fb : fb;
            st.y = a4.y ? ev.y * rinv + fb : fb;
            st.z = a4.z ? ev.z * rinv + fb : fb;
            st.w = a4.w ? ev.w * rinv + fb : fb;
            __builtin_nontemporal_store(st, (fltx4*)(arow + (j0 * 64 + lane) * 4));
            ushort4_t bv;
            bv.x = f2bf(st.x); bv.y = f2bf(st.y);
            bv.z = f2bf(st.z); bv.w = f2bf(st.w);
            *(ushort4_t*)(lrow + (((j0 * 512) + lane * 8) ^ swz)) = bv;
        }
    }

    __syncthreads();   // LDS visibility; no global fence needed

    // ---- Phase B: h_prime(16x16) = alpha(16x1024) @ Wh(1024x16), alpha from LDS ----
    if (wave < 2) {
        const int mrow = lane & 15;
        const int quad = lane >> 4;
        const int rl   = wave * 16 + mrow;           // A-row (block-local)
        const int swz  = (rl & 7) << 4;
        char* lrow = ldsb + rl * 2048;
        const unsigned short* bbase = whb + (size_t)bh * 16384;

        fltx4 acc = {0.f, 0.f, 0.f, 0.f};
        #pragma unroll 4
        for (int ks = 0; ks < 32; ++ks) {
            short8_t afr = *(const short8_t*)(lrow + ((ks * 64 + quad * 16) ^ swz));
            short8_t bfr = *(const short8_t*)(bbase + ((ks * 64 + lane) << 3));
            acc = __builtin_amdgcn_mfma_f32_16x16x32_bf16(afr, bfr, acc, 0, 0, 0);
        }

        // C layout: col = mrow (=d), row = quad*4 + reg
        #pragma unroll
        for (int r = 0; r < 4; ++r) {
            int i = i0 + wave * 16 + quad * 4 + r;
            float v = acc[r] > 0.f ? acc[r] : 0.f;
            out0[((size_t)(b * 1024 + i)) * 128 + h * 16 + mrow] = v;
        }
    }
}

// ---------------------------------------------------------------------------
// Fallback: fused kernel (known correct), used if ws_size too small.
// ---------------------------------------------------------------------------
__global__ __launch_bounds__(256) void gat_fused(
    const float* __restrict__ x, const int* __restrict__ adj,
    const float* __restrict__ W, const float* __restrict__ a,
    float* __restrict__ out0, float* __restrict__ out1)
{
    __shared__ __align__(16) unsigned short whb[32 * 64 * 8];
    __shared__ __align__(16) float ej_lds[1024];
    __shared__ float ei_lds[64];
    __shared__ float wa[64];

    const int bh    = blockIdx.x >> 4;
    const int chunk = blockIdx.x & 15;
    const int b     = bh >> 3;
    const int h     = bh & 7;
    const int tid   = threadIdx.x;
    const int wave  = tid >> 6;
    const int lane  = tid & 63;
    const int mrow  = lane & 15;
    const int quad  = lane >> 4;

    const float* Wp = W + h * 400;
    const float* ap = a + h * 32;
    const float* xb = x + (size_t)b * 1024 * 25;

    if (tid < 50) {
        int f = tid % 25, which = tid / 25;
        float s = 0.f;
        #pragma unroll
        for (int d = 0; d < 16; ++d) s += Wp[f * 16 + d] * ap[which * 16 + d];
        wa[which * 32 + f] = s;
    }
    __syncthreads();

    for (int s = 0; s < 4; ++s) {
        int n = tid + (s << 8);
        const float* xr = xb + n * 25;
        float xf[25];
        #pragma unroll
        for (int f = 0; f < 25; ++f) xf[f] = xr[f];
        float vi = 0.f, vj = 0.f;
        #pragma unroll
        for (int f = 0; f < 25; ++f) { vi += xf[f] * wa[f]; vj += xf[f] * wa[32 + f]; }
        ej_lds[n] = vj;
        if ((n >> 6) == chunk) ei_lds[n & 63] = vi;
        int base = (((n >> 5) * 64 + ((n >> 3) & 3) * 16) << 3) + (n & 7);
        #pragma unroll
        for (int d = 0; d < 16; ++d) {
            float s2 = 0.f;
            #pragma unroll
            for (int f = 0; f < 25; ++f) s2 += xf[f] * Wp[f * 16 + d];
            whb[base + d * 8] = f2bf(s2);
        }
    }
    __syncthreads();

    const int i0 = chunk * 64 + wave * 16;
    float* abase = out1 + (size_t)bh * 1024 * 1024;
    const fltx4* ej4 = (const fltx4*)ej_lds;

    for (int r = 0; r < 16; ++r) {
        int i = i0 + r;
        float s_ei = ei_lds[wave * 16 + r];
        const intx4* adj4 = (const intx4*)(adj + ((size_t)b * 1024 + i) * 1024);
        float p[16];
        float sum = 0.f;
        #pragma unroll
        for (int j0 = 0; j0 < 4; ++j0) {
            intx4 av = adj4[j0 * 64 + lane];
            fltx4 ev = ej4[j0 * 64 + lane];
            float p0 = av.x ? exp2f((s_ei + ev.x) * L2E) : 0.f;
            float p1 = av.y ? exp2f((s_ei + ev.y) * L2E) : 0.f;
            float p2 = av.z ? exp2f((s_ei + ev.z) * L2E) : 0.f;
            float p3 = av.w ? exp2f((s_ei + ev.w) * L2E) : 0.f;
            p[j0 * 4 + 0] = p0; p[j0 * 4 + 1] = p1;
            p[j0 * 4 + 2] = p2; p[j0 * 4 + 3] = p3;
            sum += (p0 + p1) + (p2 + p3);
        }
        #pragma unroll
        for (int off = 32; off; off >>= 1) sum += __shfl_xor(sum, off);
        float rinv;
        if (sum > 0.f) {
            rinv = __builtin_amdgcn_rcpf(sum);
        } else {
            rinv = 1.0f;
            #pragma unroll
            for (int k = 0; k < 16; ++k) p[k] = 1.0f / 1024.0f;
        }
        float* arow = abase + (size_t)i * 1024;
        #pragma unroll
        for (int j0 = 0; j0 < 4; ++j0) {
            fltx4 st;
            st.x = p[j0 * 4 + 0] * rinv; st.y = p[j0 * 4 + 1] * rinv;
            st.z = p[j0 * 4 + 2] * rinv; st.w = p[j0 * 4 + 3] * rinv;
            *(fltx4*)(arow + (j0 * 64 + lane) * 4) = st;
        }
    }

    __builtin_amdgcn_fence(__ATOMIC_ACQ_REL, "workgroup");

    const float* aptr = abase + (size_t)(i0 + mrow) * 1024 + quad * 8;
    fltx4 acc = {0.f, 0.f, 0.f, 0.f};
    for (int ks = 0; ks < 32; ++ks) {
        fltx4 a0 = *(const fltx4*)(aptr + ks * 32);
        fltx4 a1 = *(const fltx4*)(aptr + ks * 32 + 4);
        short8_t afr;
        #pragma unroll
        for (int q = 0; q < 4; ++q) {
            afr[q]     = (short)f2bf(a0[q]);
            afr[4 + q] = (short)f2bf(a1[q]);
        }
        short8_t bfr = *(const short8_t*)&whb[((ks * 64 + lane) << 3)];
        acc = __builtin_amdgcn_mfma_f32_16x16x32_bf16(afr, bfr, acc, 0, 0, 0);
    }
    #pragma unroll
    for (int r = 0; r < 4; ++r) {
        int i = i0 + quad * 4 + r;
        float v = acc[r] > 0.f ? acc[r] : 0.f;
        out0[((size_t)(b * 1024 + i)) * 128 + h * 16 + mrow] = v;
    }
}

extern "C" void kernel_launch(void* const* d_in, const int* in_sizes, int n_in,
                              void* d_out, int out_size, void* d_ws, size_t ws_size,
                              hipStream_t stream) {
    const float* x   = (const float*)d_in[0];
    const int*   adj = (const int*)d_in[1];
    const float* W   = (const float*)d_in[2];
    const float* a   = (const float*)d_in[3];

    float* out0 = (float*)d_out;                    // (8,1024,128)
    float* out1 = out0 + (size_t)8 * 1024 * 128;    // (8,8,1024,1024)

    const size_t WHB_BYTES = (size_t)64 * 16384 * 2;      // 2 MB
    const size_t EJ_BYTES  = (size_t)64 * 1024 * 4;       // 256 KB
    const size_t NEED      = WHB_BYTES + EJ_BYTES;        // 2.25 MB

    if (ws_size >= NEED) {
        unsigned short* whb = (unsigned short*)d_ws;
        float* ej_ws = (float*)((char*)d_ws + WHB_BYTES);
        prep_once<<<256, 256, 0, stream>>>(x, W, a, ej_ws, whb);
        gat_main<<<2048, 256, 0, stream>>>(adj, ej_ws, whb, out0, out1);
    } else {
        gat_fused<<<1024, 256, 0, stream>>>(x, adj, W, a, out0, out1);
    }
}